// Round 5
// baseline (77.288 us; speedup 1.0000x reference)
//
#include <hip/hip_runtime.h>

#define N_SEG 256
#define HIDDEN 512
#define NWAVES 8192
#define NW_SHIFT 13
#define NEG_INF (-__builtin_inff())

// Flat decomposition: wave wv owns rows [n*wv/8192, n*(wv+1)/8192) — contiguous,
// perfectly balanced. Online softmax per run of equal segment id (batch sorted);
// one partial (m, d, acc[512]) per run at slot wv*rpw + (runstart - r0), which
// the merge kernel recomputes arithmetically. Depth-1 prefetch of next row +
// next batch id keeps one 2 KB load in flight under the gate/accumulate chain.
__global__ __launch_bounds__(256, 8) void fused_flat(
    const float* __restrict__ x, const float* __restrict__ W,
    const int* __restrict__ batch, float* __restrict__ pm,
    float* __restrict__ pd, float* __restrict__ pacc, int n, int rpw) {
    int wv = blockIdx.x * 4 + (threadIdx.x >> 6);
    int lane = threadIdx.x & 63;
    int r0 = (int)(((long long)n * wv) >> NW_SHIFT);
    int r1 = (int)(((long long)n * (wv + 1)) >> NW_SHIFT);
    if (r0 >= r1) return;

    float4 w0 = *(const float4*)(W + lane * 8);
    float4 w1 = *(const float4*)(W + lane * 8 + 4);

    int j0 = 0;
    float m = NEG_INF, d = 0.0f;
    float4 acc0 = make_float4(0, 0, 0, 0), acc1 = make_float4(0, 0, 0, 0);

    // load row r0 + its segment id
    const float* xr = x + (size_t)r0 * HIDDEN + lane * 8;
    float4 a0 = *(const float4*)xr;
    float4 a1 = *(const float4*)(xr + 4);
    int sg = batch[r0];
    int cur = sg;

    for (int i = r0; i < r1; ) {
        int inext = i + 1;
        float4 b0, b1;
        int sgn;
        if (inext < r1) {  // depth-1 prefetch (issued before the dependent chain)
            const float* xn = x + (size_t)inext * HIDDEN + lane * 8;
            b0 = *(const float4*)xn;
            b1 = *(const float4*)(xn + 4);
            sgn = batch[inext];
        }
        if (sg != cur) {   // wave-uniform run boundary: flush previous run
            int slot = wv * rpw + j0;
            if (lane == 0) { pm[slot] = m; pd[slot] = d; }
            float* dst = pacc + (size_t)slot * HIDDEN + lane * 8;
            *(float4*)dst = acc0; *(float4*)(dst + 4) = acc1;
            m = NEG_INF; d = 0.0f;
            acc0 = make_float4(0, 0, 0, 0); acc1 = make_float4(0, 0, 0, 0);
            cur = sg; j0 = i - r0;
        }
        // gate = dot(row, W) (bias cancels in softmax)
        float g = a0.x * w0.x + a0.y * w0.y + a0.z * w0.z + a0.w * w0.w
                + a1.x * w1.x + a1.y * w1.y + a1.z * w1.z + a1.w * w1.w;
        #pragma unroll
        for (int off = 32; off; off >>= 1) g += __shfl_xor(g, off, 64);
        float mn = fmaxf(m, g);
        float sc = __expf(m - mn);   // 0 on first row of run, 1 if max unchanged
        float p  = __expf(g - mn);
        d = d * sc + p;
        acc0.x = acc0.x * sc + p * a0.x;  acc0.y = acc0.y * sc + p * a0.y;
        acc0.z = acc0.z * sc + p * a0.z;  acc0.w = acc0.w * sc + p * a0.w;
        acc1.x = acc1.x * sc + p * a1.x;  acc1.y = acc1.y * sc + p * a1.y;
        acc1.z = acc1.z * sc + p * a1.z;  acc1.w = acc1.w * sc + p * a1.w;
        m = mn;
        a0 = b0; a1 = b1; sg = sgn; i = inext;
    }
    int slot = wv * rpw + j0;        // final run flush
    if (lane == 0) { pm[slot] = m; pd[slot] = d; }
    float* dst = pacc + (size_t)slot * HIDDEN + lane * 8;
    *(float4*)dst = acc0; *(float4*)(dst + 4) = acc1;
}

__device__ __forceinline__ int wave_of(int r, int n) {
    int wv = (int)(((long long)r << NW_SHIFT) / n);
    while ((int)(((long long)n * (wv + 1)) >> NW_SHIFT) <= r) ++wv;
    while ((int)(((long long)n * wv) >> NW_SHIFT) > r) --wv;
    return wv;
}

// One block per (segment, half-row): binary-search segment bounds, locate all
// contributing wave partials arithmetically, softmax-merge, write 256 columns.
__global__ __launch_bounds__(256) void merge_flat(
    const int* __restrict__ batch, const float* __restrict__ pm,
    const float* __restrict__ pd, const float* __restrict__ pacc,
    float* __restrict__ out, int n, int rpw) {
    int s = blockIdx.x >> 1;
    int col = ((blockIdx.x & 1) << 8) + threadIdx.x;

    int lo = 0, hi = n;
    while (lo < hi) { int mid = (lo + hi) >> 1; if (batch[mid] < s) lo = mid + 1; else hi = mid; }
    int ss = lo; hi = n;
    while (lo < hi) { int mid = (lo + hi) >> 1; if (batch[mid] < s + 1) lo = mid + 1; else hi = mid; }
    int se = lo;
    if (ss >= se) { out[s * HIDDEN + col] = 0.0f; return; }  // empty segment

    int wlo = wave_of(ss, n), whi = wave_of(se - 1, n);

    float M = NEG_INF;
    for (int wv = wlo; wv <= whi; ++wv) {
        int wr0 = (int)(((long long)n * wv) >> NW_SHIFT);
        int wr1 = (int)(((long long)n * (wv + 1)) >> NW_SHIFT);
        if (wr0 >= wr1) continue;
        int st = ss > wr0 ? ss : wr0;
        M = fmaxf(M, pm[wv * rpw + (st - wr0)]);
    }
    float D = 0.0f;
    for (int wv = wlo; wv <= whi; ++wv) {
        int wr0 = (int)(((long long)n * wv) >> NW_SHIFT);
        int wr1 = (int)(((long long)n * (wv + 1)) >> NW_SHIFT);
        if (wr0 >= wr1) continue;
        int st = ss > wr0 ? ss : wr0;
        int slot = wv * rpw + (st - wr0);
        D += pd[slot] * __expf(pm[slot] - M);
    }
    float invD = 1.0f / (D + 1e-16f);
    float num = 0.0f;
    for (int wv = wlo; wv <= whi; ++wv) {
        int wr0 = (int)(((long long)n * wv) >> NW_SHIFT);
        int wr1 = (int)(((long long)n * (wv + 1)) >> NW_SHIFT);
        if (wr0 >= wr1) continue;
        int st = ss > wr0 ? ss : wr0;
        int slot = wv * rpw + (st - wr0);
        num += pacc[(size_t)slot * HIDDEN + col] * __expf(pm[slot] - M);
    }
    out[s * HIDDEN + col] = num * invD;
}

extern "C" void kernel_launch(void* const* d_in, const int* in_sizes, int n_in,
                              void* d_out, int out_size, void* d_ws, size_t ws_size,
                              hipStream_t stream) {
    const float* x     = (const float*)d_in[0];
    const int*   batch = (const int*)d_in[1];
    const float* W     = (const float*)d_in[2];
    int n = in_sizes[1];
    float* out = (float*)d_out;

    int rpw = (n + NWAVES - 1) >> NW_SHIFT;  // max rows (=slots) per wave
    // ws: pm[NWAVES*rpw] | pd[NWAVES*rpw] | pacc[NWAVES*rpw*512]  (~219 MB)
    float* pm   = (float*)d_ws;
    float* pd   = pm + (size_t)NWAVES * rpw;
    float* pacc = pd + (size_t)NWAVES * rpw;

    fused_flat<<<NWAVES / 4, 256, 0, stream>>>(x, W, batch, pm, pd, pacc, n, rpw);
    merge_flat<<<N_SEG * 2, 256, 0, stream>>>(batch, pm, pd, pacc, out, n, rpw);
}

// Round 6
// 58.631 us; speedup vs baseline: 1.3182x; 1.3182x over previous
//
#include <hip/hip_runtime.h>

#define N_SEG 256
#define HIDDEN 512
#define CL 32            // uniform rows per block (chunk length)
#define NEG_INF (-__builtin_inff())

// One block: seg_off[0..256] by binary search; blockbase = exclusive prefix
// sum of ceil(seg_len/CL) so fused/merge can map block <-> (segment, chunk).
__global__ __launch_bounds__(256) void bounds_kernel(
    const int* __restrict__ batch, int* __restrict__ seg_off,
    int* __restrict__ blockbase, int n) {
    __shared__ int soff[N_SEG + 1];
    __shared__ int sc[N_SEG];
    int t = threadIdx.x;
    for (int sid = t; sid <= N_SEG; sid += 256) {
        int lo = 0, hi = n;
        while (lo < hi) { int mid = (lo + hi) >> 1; if (batch[mid] < sid) lo = mid + 1; else hi = mid; }
        soff[sid] = lo;
        seg_off[sid] = lo;
    }
    __syncthreads();
    sc[t] = (soff[t + 1] - soff[t] + CL - 1) / CL;
    __syncthreads();
    for (int off = 1; off < N_SEG; off <<= 1) {   // Hillis-Steele inclusive scan
        int v = (t >= off) ? sc[t - off] : 0;
        __syncthreads();
        sc[t] += v;
        __syncthreads();
    }
    blockbase[t + 1] = sc[t];
    if (t == 0) blockbase[0] = 0;
}

// One block per uniform 32-row chunk of one segment. 4 waves march interleaved
// (wave w takes rows st+w, st+w+4, ...) so the block forms ONE sequential
// stream with 8KB effective bursts. Online softmax per wave, depth-1 prefetch,
// LDS merge of the 4 waves, one partial (m,d,acc[512]) at slot = blockIdx.x.
__global__ __launch_bounds__(256) void fused_kernel(
    const float* __restrict__ x, const float* __restrict__ W,
    const int* __restrict__ seg_off, const int* __restrict__ blockbase,
    float* __restrict__ pacc, float* __restrict__ pm, float* __restrict__ pd) {
    int b = blockIdx.x;
    if (b >= blockbase[N_SEG]) return;
    int lo = 0, hi = N_SEG;
    while (hi - lo > 1) { int mid = (lo + hi) >> 1; if (blockbase[mid] <= b) lo = mid; else hi = mid; }
    int s = lo;
    int ss = seg_off[s], se = seg_off[s + 1];
    int st = ss + (b - blockbase[s]) * CL;
    int en = st + CL < se ? st + CL : se;

    int t = threadIdx.x, lane = t & 63, w = t >> 6;
    float4 w0 = *(const float4*)(W + lane * 8);
    float4 w1 = *(const float4*)(W + lane * 8 + 4);
    float m = NEG_INF, d = 0.0f;
    float acc[8] = {0, 0, 0, 0, 0, 0, 0, 0};

    int i = st + w;
    bool have = i < en;   // wave-uniform
    float4 a0, a1;
    if (have) {
        const float* xr = x + (size_t)i * HIDDEN + lane * 8;
        a0 = *(const float4*)xr; a1 = *(const float4*)(xr + 4);
    }
    while (have) {
        int inext = i + 4;
        bool hnext = inext < en;
        float4 b0, b1;
        if (hnext) {  // depth-1 prefetch of next owned row
            const float* xr = x + (size_t)inext * HIDDEN + lane * 8;
            b0 = *(const float4*)xr; b1 = *(const float4*)(xr + 4);
        }
        float g = a0.x * w0.x + a0.y * w0.y + a0.z * w0.z + a0.w * w0.w
                + a1.x * w1.x + a1.y * w1.y + a1.z * w1.z + a1.w * w1.w;
        #pragma unroll
        for (int off = 32; off; off >>= 1) g += __shfl_xor(g, off, 64);
        float mn = fmaxf(m, g);
        float scale = __expf(m - mn);  // 0 on first row (m=-inf), 1 if max unchanged
        float p = __expf(g - mn);
        d = d * scale + p;
        acc[0] = acc[0] * scale + p * a0.x;  acc[1] = acc[1] * scale + p * a0.y;
        acc[2] = acc[2] * scale + p * a0.z;  acc[3] = acc[3] * scale + p * a0.w;
        acc[4] = acc[4] * scale + p * a1.x;  acc[5] = acc[5] * scale + p * a1.y;
        acc[6] = acc[6] * scale + p * a1.z;  acc[7] = acc[7] * scale + p * a1.w;
        m = mn;
        a0 = b0; a1 = b1; i = inext; have = hnext;
    }

    // block-level softmax merge of the 4 waves via LDS
    __shared__ float sm[4], sd[4];
    __shared__ float sacc[4][HIDDEN];  // 8 KB
    if (lane == 0) sm[w] = m;
    __syncthreads();
    float M = fmaxf(fmaxf(sm[0], sm[1]), fmaxf(sm[2], sm[3]));  // wave 0 nonempty -> finite
    float scale = (m == NEG_INF) ? 0.0f : __expf(m - M);
    if (lane == 0) sd[w] = d * scale;
    #pragma unroll
    for (int j = 0; j < 8; ++j) sacc[w][lane * 8 + j] = acc[j] * scale;
    __syncthreads();
    if (t == 0) { pm[b] = M; pd[b] = sd[0] + sd[1] + sd[2] + sd[3]; }
    for (int j = t; j < HIDDEN; j += 256)
        pacc[(size_t)b * HIDDEN + j] = sacc[0][j] + sacc[1][j] + sacc[2][j] + sacc[3][j];
}

// One block per segment: softmax-merge its contiguous slot range, write out.
__global__ __launch_bounds__(256) void merge_kernel(
    const int* __restrict__ blockbase, const float* __restrict__ pacc,
    const float* __restrict__ pm, const float* __restrict__ pd,
    float* __restrict__ out) {
    int s = blockIdx.x, t = threadIdx.x;
    int k0 = blockbase[s], k1 = blockbase[s + 1];
    float M = NEG_INF;
    for (int k = k0; k < k1; ++k) M = fmaxf(M, pm[k]);
    float D = 0.0f;
    for (int k = k0; k < k1; ++k) D += pd[k] * __expf(pm[k] - M);
    float invD = 1.0f / (D + 1e-16f);
    #pragma unroll
    for (int rep = 0; rep < 2; ++rep) {
        int col = t + rep * 256;
        float num = 0.0f;
        for (int k = k0; k < k1; ++k)
            num += pacc[(size_t)k * HIDDEN + col] * __expf(pm[k] - M);
        out[s * HIDDEN + col] = num * invD;  // empty segment (k0==k1) -> 0
    }
}

extern "C" void kernel_launch(void* const* d_in, const int* in_sizes, int n_in,
                              void* d_out, int out_size, void* d_ws, size_t ws_size,
                              hipStream_t stream) {
    const float* x     = (const float*)d_in[0];
    const int*   batch = (const int*)d_in[1];
    const float* W     = (const float*)d_in[2];
    int n = in_sizes[1];
    float* out = (float*)d_out;

    int nb = (n + CL - 1) / CL + N_SEG;  // upper bound on total blocks
    // ws: pacc[nb*512] (16B-aligned first) | pm[nb] | pd[nb] | seg_off[257] | blockbase[257]
    float* pacc = (float*)d_ws;
    float* pm   = pacc + (size_t)nb * HIDDEN;
    float* pd   = pm + nb;
    int* seg_off   = (int*)(pd + nb);
    int* blockbase = seg_off + (N_SEG + 1);

    bounds_kernel<<<1, 256, 0, stream>>>(batch, seg_off, blockbase, n);
    fused_kernel<<<nb, 256, 0, stream>>>(x, W, seg_off, blockbase, pacc, pm, pd);
    merge_kernel<<<N_SEG, 256, 0, stream>>>(blockbase, pacc, pm, pd, out);
}

// Round 7
// 48.097 us; speedup vs baseline: 1.6069x; 1.2190x over previous
//
#include <hip/hip_runtime.h>

#define N_SEG 256
#define HIDDEN 512
#define CHUNKS 16        // chunks per segment
#define NEG_INF (-__builtin_inff())

// One block per (segment, chunk): block binary-searches its own segment bounds
// (concurrent, L2-hot), takes the c-th 1/16 slice, streams it with 4 waves
// interleaved (wave w: rows st+w, st+w+4, ... -> one sequential ~8KB-burst
// stream per block), online softmax per wave with depth-1 prefetch, LDS merge,
// one partial (m, d, acc[512]) at slot = blockIdx.x.
__global__ __launch_bounds__(256) void fused_kernel(
    const float* __restrict__ x, const float* __restrict__ W,
    const int* __restrict__ batch,
    float* __restrict__ pacc, float* __restrict__ pm, float* __restrict__ pd,
    int n) {
    int b = blockIdx.x;
    int s = b >> 4, c = b & 15;
    int t = threadIdx.x, lane = t & 63, w = t >> 6;

    // segment bounds via 2 binary searches over sorted batch
    int lo = 0, hi = n;
    while (lo < hi) { int mid = (lo + hi) >> 1; if (batch[mid] < s) lo = mid + 1; else hi = mid; }
    int ss = lo; hi = n;
    while (lo < hi) { int mid = (lo + hi) >> 1; if (batch[mid] < s + 1) lo = mid + 1; else hi = mid; }
    int se = lo;
    int len = se - ss;
    int st = ss + (int)(((long long)len * c) >> 4);
    int en = ss + (int)(((long long)len * (c + 1)) >> 4);

    if (st >= en) {  // empty chunk: neutral partial
        if (t == 0) { pm[b] = NEG_INF; pd[b] = 0.0f; }
        for (int j = t; j < HIDDEN; j += 256) pacc[(size_t)b * HIDDEN + j] = 0.0f;
        return;
    }

    float4 w0 = *(const float4*)(W + lane * 8);
    float4 w1 = *(const float4*)(W + lane * 8 + 4);
    float m = NEG_INF, d = 0.0f;
    float acc[8] = {0, 0, 0, 0, 0, 0, 0, 0};

    int i = st + w;
    bool have = i < en;   // wave-uniform
    float4 a0, a1;
    if (have) {
        const float* xr = x + (size_t)i * HIDDEN + lane * 8;
        a0 = *(const float4*)xr; a1 = *(const float4*)(xr + 4);
    }
    while (have) {
        int inext = i + 4;
        bool hnext = inext < en;
        float4 b0, b1;
        if (hnext) {  // depth-1 prefetch of next owned row
            const float* xr = x + (size_t)inext * HIDDEN + lane * 8;
            b0 = *(const float4*)xr; b1 = *(const float4*)(xr + 4);
        }
        float g = a0.x * w0.x + a0.y * w0.y + a0.z * w0.z + a0.w * w0.w
                + a1.x * w1.x + a1.y * w1.y + a1.z * w1.z + a1.w * w1.w;
        #pragma unroll
        for (int off = 32; off; off >>= 1) g += __shfl_xor(g, off, 64);
        float mn = fmaxf(m, g);
        float scale = __expf(m - mn);  // 0 on first row (m=-inf), 1 if max unchanged
        float p = __expf(g - mn);
        d = d * scale + p;
        acc[0] = acc[0] * scale + p * a0.x;  acc[1] = acc[1] * scale + p * a0.y;
        acc[2] = acc[2] * scale + p * a0.z;  acc[3] = acc[3] * scale + p * a0.w;
        acc[4] = acc[4] * scale + p * a1.x;  acc[5] = acc[5] * scale + p * a1.y;
        acc[6] = acc[6] * scale + p * a1.z;  acc[7] = acc[7] * scale + p * a1.w;
        m = mn;
        a0 = b0; a1 = b1; i = inext; have = hnext;
    }

    // block-level softmax merge of the 4 waves via LDS
    __shared__ float sm[4], sd[4];
    __shared__ float sacc[4][HIDDEN];  // 8 KB
    if (lane == 0) sm[w] = m;
    __syncthreads();
    float M = fmaxf(fmaxf(sm[0], sm[1]), fmaxf(sm[2], sm[3]));  // wave 0 nonempty -> finite
    float scale = (m == NEG_INF) ? 0.0f : __expf(m - M);
    if (lane == 0) sd[w] = d * scale;
    #pragma unroll
    for (int j = 0; j < 8; ++j) sacc[w][lane * 8 + j] = acc[j] * scale;
    __syncthreads();
    if (t == 0) { pm[b] = M; pd[b] = sd[0] + sd[1] + sd[2] + sd[3]; }
    for (int j = t; j < HIDDEN; j += 256)
        pacc[(size_t)b * HIDDEN + j] = sacc[0][j] + sacc[1][j] + sacc[2][j] + sacc[3][j];
}

// One block per segment: softmax-merge its 16 fixed slots [16s, 16s+16), write out.
// No batch access, no searches. Empty chunks have pm=-inf -> weight 0.
__global__ __launch_bounds__(256) void merge_kernel(
    const float* __restrict__ pacc, const float* __restrict__ pm,
    const float* __restrict__ pd, float* __restrict__ out) {
    int s = blockIdx.x, t = threadIdx.x;
    int k0 = s * CHUNKS;
    float M = NEG_INF;
    #pragma unroll
    for (int k = 0; k < CHUNKS; ++k) M = fmaxf(M, pm[k0 + k]);
    float wts[CHUNKS];
    float D = 0.0f;
    #pragma unroll
    for (int k = 0; k < CHUNKS; ++k) {
        float mk = pm[k0 + k];
        float wk = (mk == NEG_INF) ? 0.0f : __expf(mk - M);  // also guards empty segment (M=-inf)
        wts[k] = wk;
        D += pd[k0 + k] * wk;
    }
    float invD = 1.0f / (D + 1e-16f);
    #pragma unroll
    for (int rep = 0; rep < 2; ++rep) {
        int col = t + rep * 256;
        float num = 0.0f;
        #pragma unroll
        for (int k = 0; k < CHUNKS; ++k)
            num += pacc[(size_t)(k0 + k) * HIDDEN + col] * wts[k];
        out[s * HIDDEN + col] = num * invD;  // empty segment -> 0
    }
}

extern "C" void kernel_launch(void* const* d_in, const int* in_sizes, int n_in,
                              void* d_out, int out_size, void* d_ws, size_t ws_size,
                              hipStream_t stream) {
    const float* x     = (const float*)d_in[0];
    const int*   batch = (const int*)d_in[1];
    const float* W     = (const float*)d_in[2];
    int n = in_sizes[1];
    float* out = (float*)d_out;

    const int nb = N_SEG * CHUNKS;  // 4096
    // ws: pacc[nb*512] (16B-aligned first) | pm[nb] | pd[nb]
    float* pacc = (float*)d_ws;
    float* pm   = pacc + (size_t)nb * HIDDEN;
    float* pd   = pm + nb;

    fused_kernel<<<nb, 256, 0, stream>>>(x, W, batch, pacc, pm, pd, n);
    merge_kernel<<<N_SEG, 256, 0, stream>>>(pacc, pm, pd, out);
}